// Round 1
// baseline (304.745 us; speedup 1.0000x reference)
//
#include <hip/hip_runtime.h>
#include <math.h>

typedef unsigned short u16;
typedef __attribute__((ext_vector_type(8))) short short8;
typedef __attribute__((ext_vector_type(4))) float f32x4;
typedef __attribute__((ext_vector_type(4))) unsigned int u32x4;
typedef __attribute__((ext_vector_type(4))) unsigned short u16x4;

#define N_TOK 2048
#define DIM 1024
#define NE 8
#define NSLOT 6144          // 4096 routed capacity + 2048 shared
#define OUT_ELEMS 2097152   // N_TOK * DIM

__device__ __forceinline__ u16 f2bf(float f) {
    union { float f; unsigned u; } v; v.f = f;
    unsigned r = (v.u + 0x7FFFu + ((v.u >> 16) & 1u)) >> 16;
    return (u16)r;
}

// ---------------- init: zero out (+aux), fill shared token list, cursors ----
__global__ void k_init(float* __restrict__ out, int* __restrict__ tlist,
                       float* __restrict__ wlist, int* __restrict__ curs) {
    int i = blockIdx.x * 256 + threadIdx.x;
    if (i <= OUT_ELEMS) out[i] = 0.f;
    if (i < NSLOT) {
        if (i >= 4096) { tlist[i] = i - 4096; wlist[i] = 1.f; }
        else           { tlist[i] = 0;        wlist[i] = 0.f; }
    }
    if (i < 16) curs[i] = 0;
}

// ---------------- x fp32 -> bf16 ----------------
__global__ void k_cvt_x(const float* __restrict__ x, u16* __restrict__ xb) {
    int i = blockIdx.x * 256 + threadIdx.x;     // one thread = 4 elems
    f32x4 v = ((const f32x4*)x)[i];
    u16x4 o;
    o.x = f2bf(v.x); o.y = f2bf(v.y); o.z = f2bf(v.z); o.w = f2bf(v.w);
    ((u16x4*)xb)[i] = o;
}

// ------------- weights: fp32 [K,N] -> bf16 transposed [N,K] ----------------
// 27 matrices of 1024x1024: wg(8), wu(8), wd(8), ws_g, ws_u, ws_d
__global__ void k_cvt_w(const float* __restrict__ wg, const float* __restrict__ wu,
                        const float* __restrict__ wd, const float* __restrict__ wsg,
                        const float* __restrict__ wsu, const float* __restrict__ wsd,
                        u16* __restrict__ wgt, u16* __restrict__ wut,
                        u16* __restrict__ wdt, u16* __restrict__ wsgt,
                        u16* __restrict__ wsut, u16* __restrict__ wsdt) {
    __shared__ float tile[32][33];
    int bx = blockIdx.x;
    int mat = bx >> 10;
    int tl  = bx & 1023;
    int tr = tl >> 5, tc = tl & 31;
    const float* src; u16* dst;
    if      (mat <  8) { src = wg  + (size_t)mat * 1048576;        dst = wgt + (size_t)mat * 1048576; }
    else if (mat < 16) { src = wu  + (size_t)(mat - 8) * 1048576;  dst = wut + (size_t)(mat - 8) * 1048576; }
    else if (mat < 24) { src = wd  + (size_t)(mat - 16) * 1048576; dst = wdt + (size_t)(mat - 16) * 1048576; }
    else if (mat == 24){ src = wsg; dst = wsgt; }
    else if (mat == 25){ src = wsu; dst = wsut; }
    else               { src = wsd; dst = wsdt; }
    int tx = threadIdx.x & 31, ty = threadIdx.x >> 5;
#pragma unroll
    for (int j = 0; j < 4; j++)
        tile[ty + j * 8][tx] = src[(size_t)(tr * 32 + ty + j * 8) * 1024 + tc * 32 + tx];
    __syncthreads();
#pragma unroll
    for (int j = 0; j < 4; j++)
        dst[(size_t)(tc * 32 + ty + j * 8) * 1024 + tr * 32 + tx] = f2bf(tile[tx][ty + j * 8]);
}

// ---------------- router: logits, top-2, softmax P ----------------
__global__ void k_router(const float* __restrict__ x, const float* __restrict__ wgate,
                         float* __restrict__ Ptok, int* __restrict__ tidx,
                         float* __restrict__ tw) {
    int wave = threadIdx.x >> 6;
    int lane = threadIdx.x & 63;
    int n = blockIdx.x * 4 + wave;
    const float* xr = x + (size_t)n * DIM;
    float acc[8] = {0.f,0.f,0.f,0.f,0.f,0.f,0.f,0.f};
    for (int d = lane; d < DIM; d += 64) {
        float xv = xr[d];
        const float* wr = wgate + d * 8;
#pragma unroll
        for (int e = 0; e < 8; e++) acc[e] += xv * wr[e];
    }
#pragma unroll
    for (int off = 32; off; off >>= 1) {
#pragma unroll
        for (int e = 0; e < 8; e++) acc[e] += __shfl_xor(acc[e], off);
    }
    if (lane == 0) {
        float mx = acc[0];
#pragma unroll
        for (int e = 1; e < 8; e++) mx = fmaxf(mx, acc[e]);
        float p[8], s = 0.f;
#pragma unroll
        for (int e = 0; e < 8; e++) { p[e] = expf(acc[e] - mx); s += p[e]; }
        float inv = 1.f / s;
#pragma unroll
        for (int e = 0; e < 8; e++) Ptok[n * 8 + e] = p[e] * inv;
        int i0 = 0; float b0 = acc[0];
#pragma unroll
        for (int e = 1; e < 8; e++) if (acc[e] > b0) { b0 = acc[e]; i0 = e; }
        int i1 = -1; float b1 = -3.4e38f;
#pragma unroll
        for (int e = 0; e < 8; e++) if (e != i0 && acc[e] > b1) { b1 = acc[e]; i1 = e; }
        float w0 = 1.f / (1.f + expf(b1 - b0));
        tidx[n * 2] = i0; tidx[n * 2 + 1] = i1;
        tw[n * 2] = w0;   tw[n * 2 + 1] = 1.f - w0;
    }
}

// -------- single-block: P-sum, counts, aux loss, offsets ----------
__global__ void k_reduce(const float* __restrict__ Ptok, const int* __restrict__ tidx,
                         float* __restrict__ out, int* __restrict__ counts,
                         int* __restrict__ offs) {
    __shared__ float ps[256][8];
    __shared__ int cnt[8];
    int t = threadIdx.x;
    if (t < 8) cnt[t] = 0;
    __syncthreads();
    float p[8] = {0.f,0.f,0.f,0.f,0.f,0.f,0.f,0.f};
    for (int n = t; n < N_TOK; n += 256) {
#pragma unroll
        for (int e = 0; e < 8; e++) p[e] += Ptok[n * 8 + e];
        atomicAdd(&cnt[tidx[n * 2]], 1);
        atomicAdd(&cnt[tidx[n * 2 + 1]], 1);
    }
#pragma unroll
    for (int e = 0; e < 8; e++) ps[t][e] = p[e];
    __syncthreads();
    for (int off = 128; off; off >>= 1) {
        if (t < off) {
#pragma unroll
            for (int e = 0; e < 8; e++) ps[t][e] += ps[t + off][e];
        }
        __syncthreads();
    }
    if (t == 0) {
        float aux = 0.f;
        for (int e = 0; e < 8; e++)
            aux += ((float)cnt[e] / (float)N_TOK) * (ps[0][e] / (float)N_TOK);
        out[OUT_ELEMS] = 8.f * aux;
        int o = 0;
        for (int e = 0; e < 8; e++) { offs[e] = o; counts[e] = cnt[e]; o += cnt[e]; }
        offs[8] = 4096; counts[8] = 2048;
    }
}

// ---------------- scatter tokens into expert lists ----------------
__global__ void k_scatter(const int* __restrict__ tidx, const float* __restrict__ tw,
                          const int* __restrict__ offs, int* __restrict__ curs,
                          int* __restrict__ tlist, float* __restrict__ wlist) {
    int n = blockIdx.x * 256 + threadIdx.x;
    if (n >= N_TOK) return;
#pragma unroll
    for (int k = 0; k < 2; k++) {
        int e = tidx[n * 2 + k];
        int p = atomicAdd(&curs[e], 1);
        int sl = offs[e] + p;
        tlist[sl] = n;
        wlist[sl] = tw[n * 2 + k];
    }
}

// ---------------- GEMM1: gathered X @ [Wg|Wu], fused silu*u -> H bf16 -------
// jobs 0..7 routed experts, job 8 shared. 128x128 tile, K=1024, BK=32.
__global__ __launch_bounds__(256, 2)
void k_gemm1(const u16* __restrict__ xb, const u16* __restrict__ wgt,
             const u16* __restrict__ wut, const u16* __restrict__ wsgt,
             const u16* __restrict__ wsut, const int* __restrict__ tlist,
             const int* __restrict__ counts, const int* __restrict__ offs,
             u16* __restrict__ H) {
    int bx = blockIdx.x;
    int job = bx >> 7;
    int mt = (bx >> 3) & 15;
    int nt = bx & 7;
    int jcnt = counts[job];
    int m0 = mt << 7;
    if (m0 >= jcnt) return;
    int joff = offs[job];
    int n0 = nt << 7;
    const u16* Bg; const u16* Bu;
    if (job < 8) { Bg = wgt + (size_t)job * 1048576; Bu = wut + (size_t)job * 1048576; }
    else         { Bg = wsgt; Bu = wsut; }

    __shared__ __attribute__((aligned(16))) u16 As[128 * 40];
    __shared__ __attribute__((aligned(16))) u16 Bgs[128 * 40];
    __shared__ __attribute__((aligned(16))) u16 Bus[128 * 40];

    int t = threadIdx.x;
    int r = t >> 1;
    int ch = (t & 1) << 4;          // 0 or 16
    int tok = tlist[joff + m0 + r];
    const u16* agp = xb + (size_t)tok * 1024 + ch;
    const u16* bgp = Bg + (size_t)(n0 + r) * 1024 + ch;
    const u16* bup = Bu + (size_t)(n0 + r) * 1024 + ch;
    u16* asp  = As  + r * 40 + ch;
    u16* bgsp = Bgs + r * 40 + ch;
    u16* busp = Bus + r * 40 + ch;

    int wave = t >> 6, lane = t & 63;
    int wm = (wave >> 1) << 6, wn = (wave & 1) << 6;
    int quad = lane >> 4, lr = lane & 15;

    f32x4 accg[4][4], accu[4][4];
    f32x4 zz = {0.f, 0.f, 0.f, 0.f};
#pragma unroll
    for (int i = 0; i < 4; i++)
#pragma unroll
        for (int j = 0; j < 4; j++) { accg[i][j] = zz; accu[i][j] = zz; }

    for (int k0 = 0; k0 < 1024; k0 += 32) {
        *(u32x4*)(asp)      = *(const u32x4*)(agp + k0);
        *(u32x4*)(asp + 8)  = *(const u32x4*)(agp + k0 + 8);
        *(u32x4*)(bgsp)     = *(const u32x4*)(bgp + k0);
        *(u32x4*)(bgsp + 8) = *(const u32x4*)(bgp + k0 + 8);
        *(u32x4*)(busp)     = *(const u32x4*)(bup + k0);
        *(u32x4*)(busp + 8) = *(const u32x4*)(bup + k0 + 8);
        __syncthreads();
        short8 af[4], bgf[4], buf[4];
#pragma unroll
        for (int i = 0; i < 4; i++) {
            af[i]  = *(const short8*)(As  + (wm + i * 16 + lr) * 40 + quad * 8);
            bgf[i] = *(const short8*)(Bgs + (wn + i * 16 + lr) * 40 + quad * 8);
            buf[i] = *(const short8*)(Bus + (wn + i * 16 + lr) * 40 + quad * 8);
        }
#pragma unroll
        for (int mi = 0; mi < 4; mi++)
#pragma unroll
            for (int ni = 0; ni < 4; ni++) {
                accg[mi][ni] = __builtin_amdgcn_mfma_f32_16x16x32_bf16(af[mi], bgf[ni], accg[mi][ni], 0, 0, 0);
                accu[mi][ni] = __builtin_amdgcn_mfma_f32_16x16x32_bf16(af[mi], buf[ni], accu[mi][ni], 0, 0, 0);
            }
        __syncthreads();
    }
    // epilogue: h = silu(g)*u -> bf16 H
#pragma unroll
    for (int mi = 0; mi < 4; mi++) {
        int rowb = m0 + wm + mi * 16 + quad * 4;
#pragma unroll
        for (int rr = 0; rr < 4; rr++) {
            int row = rowb + rr;
            if (row < jcnt) {
                size_t base = (size_t)(joff + row) * 1024 + n0 + wn;
#pragma unroll
                for (int ni = 0; ni < 4; ni++) {
                    float g = accg[mi][ni][rr];
                    float u = accu[mi][ni][rr];
                    float h = (g / (1.f + expf(-g))) * u;
                    H[base + ni * 16 + lr] = f2bf(h);
                }
            }
        }
    }
}

// ---------------- GEMM2: H @ Wd, scale by token weight, atomicAdd out -------
__global__ __launch_bounds__(256, 2)
void k_gemm2(const u16* __restrict__ H, const u16* __restrict__ wdt,
             const u16* __restrict__ wsdt, const int* __restrict__ tlist,
             const float* __restrict__ wlist, const int* __restrict__ counts,
             const int* __restrict__ offs, float* __restrict__ out) {
    int bx = blockIdx.x;
    int job = bx >> 7;
    int mt = (bx >> 3) & 15;
    int nt = bx & 7;
    int jcnt = counts[job];
    int m0 = mt << 7;
    if (m0 >= jcnt) return;
    int joff = offs[job];
    int n0 = nt << 7;
    const u16* Bt = (job < 8) ? (wdt + (size_t)job * 1048576) : wsdt;

    __shared__ __attribute__((aligned(16))) u16 As[128 * 40];
    __shared__ __attribute__((aligned(16))) u16 Bs[128 * 40];

    int t = threadIdx.x;
    int r = t >> 1;
    int ch = (t & 1) << 4;
    const u16* agp = H  + (size_t)(joff + m0 + r) * 1024 + ch;
    const u16* bbp = Bt + (size_t)(n0 + r) * 1024 + ch;
    u16* asp = As + r * 40 + ch;
    u16* bsp = Bs + r * 40 + ch;

    int wave = t >> 6, lane = t & 63;
    int wm = (wave >> 1) << 6, wn = (wave & 1) << 6;
    int quad = lane >> 4, lr = lane & 15;

    f32x4 acc[4][4];
    f32x4 zz = {0.f, 0.f, 0.f, 0.f};
#pragma unroll
    for (int i = 0; i < 4; i++)
#pragma unroll
        for (int j = 0; j < 4; j++) acc[i][j] = zz;

    for (int k0 = 0; k0 < 1024; k0 += 32) {
        *(u32x4*)(asp)     = *(const u32x4*)(agp + k0);
        *(u32x4*)(asp + 8) = *(const u32x4*)(agp + k0 + 8);
        *(u32x4*)(bsp)     = *(const u32x4*)(bbp + k0);
        *(u32x4*)(bsp + 8) = *(const u32x4*)(bbp + k0 + 8);
        __syncthreads();
        short8 af[4], bf[4];
#pragma unroll
        for (int i = 0; i < 4; i++) {
            af[i] = *(const short8*)(As + (wm + i * 16 + lr) * 40 + quad * 8);
            bf[i] = *(const short8*)(Bs + (wn + i * 16 + lr) * 40 + quad * 8);
        }
#pragma unroll
        for (int mi = 0; mi < 4; mi++)
#pragma unroll
            for (int ni = 0; ni < 4; ni++)
                acc[mi][ni] = __builtin_amdgcn_mfma_f32_16x16x32_bf16(af[mi], bf[ni], acc[mi][ni], 0, 0, 0);
        __syncthreads();
    }
#pragma unroll
    for (int mi = 0; mi < 4; mi++) {
        int rowb = m0 + wm + mi * 16 + quad * 4;
#pragma unroll
        for (int rr = 0; rr < 4; rr++) {
            int row = rowb + rr;
            if (row < jcnt) {
                int sl = joff + row;
                int tokn = tlist[sl];
                float w = wlist[sl];
                float* orow = out + (size_t)tokn * 1024 + n0 + wn;
#pragma unroll
                for (int ni = 0; ni < 4; ni++)
                    atomicAdd(&orow[ni * 16 + lr], acc[mi][ni][rr] * w);
            }
        }
    }
}

extern "C" void kernel_launch(void* const* d_in, const int* in_sizes, int n_in,
                              void* d_out, int out_size, void* d_ws, size_t ws_size,
                              hipStream_t stream) {
    const float* x     = (const float*)d_in[0];
    const float* wgate = (const float*)d_in[1];
    const float* wg    = (const float*)d_in[2];
    const float* wu    = (const float*)d_in[3];
    const float* wd    = (const float*)d_in[4];
    const float* wsg   = (const float*)d_in[5];
    const float* wsu   = (const float*)d_in[6];
    const float* wsd   = (const float*)d_in[7];
    float* out = (float*)d_out;

    char* ws = (char*)d_ws;
    u16*   xb    = (u16*)(ws + 0);           // 4,194,304 B
    u16*   wgt   = (u16*)(ws + 4194304);     // 16 MB
    u16*   wut   = (u16*)(ws + 20971520);
    u16*   wdt   = (u16*)(ws + 37748736);
    u16*   wsgt  = (u16*)(ws + 54525952);    // 2 MB
    u16*   wsut  = (u16*)(ws + 56623104);
    u16*   wsdt  = (u16*)(ws + 58720256);
    u16*   H     = (u16*)(ws + 60817408);    // 12,582,912 B
    float* Ptok  = (float*)(ws + 73400320);
    int*   tidx  = (int*)(ws + 73465856);
    float* tw    = (float*)(ws + 73482240);
    int*   tlist = (int*)(ws + 73498624);
    float* wlist = (float*)(ws + 73523200);
    int*   counts= (int*)(ws + 73547776);
    int*   offs  = (int*)(ws + 73547840);
    int*   curs  = (int*)(ws + 73547904);

    k_init<<<8193, 256, 0, stream>>>(out, tlist, wlist, curs);
    k_cvt_x<<<2048, 256, 0, stream>>>(x, xb);
    k_cvt_w<<<27648, 256, 0, stream>>>(wg, wu, wd, wsg, wsu, wsd,
                                       wgt, wut, wdt, wsgt, wsut, wsdt);
    k_router<<<512, 256, 0, stream>>>(x, wgate, Ptok, tidx, tw);
    k_reduce<<<1, 256, 0, stream>>>(Ptok, tidx, out, counts, offs);
    k_scatter<<<8, 256, 0, stream>>>(tidx, tw, offs, curs, tlist, wlist);
    k_gemm1<<<1152, 256, 0, stream>>>(xb, wgt, wut, wsgt, wsut, tlist, counts, offs, H);
    k_gemm2<<<1152, 256, 0, stream>>>(H, wdt, wsdt, tlist, wlist, counts, offs, out);
}

// Round 2
// 284.617 us; speedup vs baseline: 1.0707x; 1.0707x over previous
//
#include <hip/hip_runtime.h>
#include <math.h>

typedef unsigned short u16;
typedef __attribute__((ext_vector_type(8))) short short8;
typedef __attribute__((ext_vector_type(4))) float f32x4;
typedef __attribute__((ext_vector_type(4))) unsigned short u16x4;

#define N_TOK 2048
#define DIM 1024
#define OUT_ELEMS 2097152   // N_TOK * DIM

#define GLDS16(gp, lp) __builtin_amdgcn_global_load_lds( \
    (const __attribute__((address_space(1))) unsigned int*)(gp), \
    (__attribute__((address_space(3))) unsigned int*)(lp), 16, 0, 0)

__device__ __forceinline__ u16 f2bf(float f) {
    union { float f; unsigned u; } v; v.f = f;
    unsigned r = (v.u + 0x7FFFu + ((v.u >> 16) & 1u)) >> 16;
    return (u16)r;
}

// ---------------- init: shared-expert token list + cursors ----------------
__global__ void k_init(int* __restrict__ tlist, int* __restrict__ curs) {
    int i = blockIdx.x * 256 + threadIdx.x;   // 0..2047
    tlist[4096 + i] = i;
    if (i < 16) curs[i] = 0;
}

// ---------------- x fp32 -> bf16 ----------------
__global__ void k_cvt_x(const float* __restrict__ x, u16* __restrict__ xb) {
    int i = blockIdx.x * 256 + threadIdx.x;     // one thread = 4 elems
    f32x4 v = ((const f32x4*)x)[i];
    u16x4 o;
    o.x = f2bf(v.x); o.y = f2bf(v.y); o.z = f2bf(v.z); o.w = f2bf(v.w);
    ((u16x4*)xb)[i] = o;
}

// ------------- weights: fp32 [K,N] -> bf16 transposed [N,K] ----------------
__global__ void k_cvt_w(const float* __restrict__ wg, const float* __restrict__ wu,
                        const float* __restrict__ wd, const float* __restrict__ wsg,
                        const float* __restrict__ wsu, const float* __restrict__ wsd,
                        u16* __restrict__ wgt, u16* __restrict__ wut,
                        u16* __restrict__ wdt, u16* __restrict__ wsgt,
                        u16* __restrict__ wsut, u16* __restrict__ wsdt) {
    __shared__ float tile[32][33];
    int bx = blockIdx.x;
    int mat = bx >> 10;
    int tl  = bx & 1023;
    int tr = tl >> 5, tc = tl & 31;
    const float* src; u16* dst;
    if      (mat <  8) { src = wg  + (size_t)mat * 1048576;        dst = wgt + (size_t)mat * 1048576; }
    else if (mat < 16) { src = wu  + (size_t)(mat - 8) * 1048576;  dst = wut + (size_t)(mat - 8) * 1048576; }
    else if (mat < 24) { src = wd  + (size_t)(mat - 16) * 1048576; dst = wdt + (size_t)(mat - 16) * 1048576; }
    else if (mat == 24){ src = wsg; dst = wsgt; }
    else if (mat == 25){ src = wsu; dst = wsut; }
    else               { src = wsd; dst = wsdt; }
    int tx = threadIdx.x & 31, ty = threadIdx.x >> 5;
#pragma unroll
    for (int j = 0; j < 4; j++)
        tile[ty + j * 8][tx] = src[(size_t)(tr * 32 + ty + j * 8) * 1024 + tc * 32 + tx];
    __syncthreads();
    int row = threadIdx.x >> 3;   // 0..31
    int c4  = threadIdx.x & 7;    // 0..7
    u16x4 o;
    o.x = f2bf(tile[c4 * 4 + 0][row]);
    o.y = f2bf(tile[c4 * 4 + 1][row]);
    o.z = f2bf(tile[c4 * 4 + 2][row]);
    o.w = f2bf(tile[c4 * 4 + 3][row]);
    *(u16x4*)(dst + (size_t)(tc * 32 + row) * 1024 + tr * 32 + c4 * 4) = o;
}

// ---------------- router: logits, top-2, softmax P ----------------
__global__ void k_router(const float* __restrict__ x, const float* __restrict__ wgate,
                         float* __restrict__ Ptok, int* __restrict__ tidx,
                         float* __restrict__ tw) {
    int wave = threadIdx.x >> 6;
    int lane = threadIdx.x & 63;
    int n = blockIdx.x * 4 + wave;
    const float* xr = x + (size_t)n * DIM;
    float acc[8] = {0.f,0.f,0.f,0.f,0.f,0.f,0.f,0.f};
    for (int d = lane; d < DIM; d += 64) {
        float xv = xr[d];
        const float* wr = wgate + d * 8;
#pragma unroll
        for (int e = 0; e < 8; e++) acc[e] += xv * wr[e];
    }
#pragma unroll
    for (int off = 32; off; off >>= 1) {
#pragma unroll
        for (int e = 0; e < 8; e++) acc[e] += __shfl_xor(acc[e], off);
    }
    if (lane == 0) {
        float mx = acc[0];
#pragma unroll
        for (int e = 1; e < 8; e++) mx = fmaxf(mx, acc[e]);
        float p[8], s = 0.f;
#pragma unroll
        for (int e = 0; e < 8; e++) { p[e] = expf(acc[e] - mx); s += p[e]; }
        float inv = 1.f / s;
#pragma unroll
        for (int e = 0; e < 8; e++) Ptok[n * 8 + e] = p[e] * inv;
        int i0 = 0; float b0 = acc[0];
#pragma unroll
        for (int e = 1; e < 8; e++) if (acc[e] > b0) { b0 = acc[e]; i0 = e; }
        int i1 = -1; float b1 = -3.4e38f;
#pragma unroll
        for (int e = 0; e < 8; e++) if (e != i0 && acc[e] > b1) { b1 = acc[e]; i1 = e; }
        float w0 = 1.f / (1.f + expf(b1 - b0));
        tidx[n * 2] = i0; tidx[n * 2 + 1] = i1;
        tw[n * 2] = w0;   tw[n * 2 + 1] = 1.f - w0;
    }
}

// -------- single-block: P-sum, counts, aux loss, offsets ----------
__global__ void k_reduce(const float* __restrict__ Ptok, const int* __restrict__ tidx,
                         float* __restrict__ out, int* __restrict__ counts,
                         int* __restrict__ offs) {
    __shared__ float ps[256][8];
    __shared__ int cnt[8];
    int t = threadIdx.x;
    if (t < 8) cnt[t] = 0;
    __syncthreads();
    float p[8] = {0.f,0.f,0.f,0.f,0.f,0.f,0.f,0.f};
    for (int n = t; n < N_TOK; n += 256) {
#pragma unroll
        for (int e = 0; e < 8; e++) p[e] += Ptok[n * 8 + e];
        atomicAdd(&cnt[tidx[n * 2]], 1);
        atomicAdd(&cnt[tidx[n * 2 + 1]], 1);
    }
#pragma unroll
    for (int e = 0; e < 8; e++) ps[t][e] = p[e];
    __syncthreads();
    for (int off = 128; off; off >>= 1) {
        if (t < off) {
#pragma unroll
            for (int e = 0; e < 8; e++) ps[t][e] += ps[t + off][e];
        }
        __syncthreads();
    }
    if (t == 0) {
        float aux = 0.f;
        for (int e = 0; e < 8; e++)
            aux += ((float)cnt[e] / (float)N_TOK) * (ps[0][e] / (float)N_TOK);
        out[OUT_ELEMS] = 8.f * aux;
        int o = 0;
        for (int e = 0; e < 8; e++) { offs[e] = o; counts[e] = cnt[e]; o += cnt[e]; }
        offs[8] = 4096; counts[8] = 2048;
    }
}

// ---------------- scatter tokens into expert lists, record slots ------------
__global__ void k_scatter(const int* __restrict__ tidx, const int* __restrict__ offs,
                          int* __restrict__ curs, int* __restrict__ tlist,
                          int* __restrict__ slots) {
    int n = blockIdx.x * 256 + threadIdx.x;
    if (n >= N_TOK) return;
#pragma unroll
    for (int k = 0; k < 2; k++) {
        int e = tidx[n * 2 + k];
        int p = atomicAdd(&curs[e], 1);
        int sl = offs[e] + p;
        tlist[sl] = n;
        slots[n * 2 + k] = sl;
    }
}

// ---------------- GEMM1: gathered X @ [Wg|Wu], fused silu*u -> H bf16 -------
// 128x128 tile, BK=32, global_load_lds width-16 staging, unpadded [128][32] LDS.
__global__ __launch_bounds__(256, 2)
void k_gemm1(const u16* __restrict__ xb, const u16* __restrict__ wgt,
             const u16* __restrict__ wut, const u16* __restrict__ wsgt,
             const u16* __restrict__ wsut, const int* __restrict__ tlist,
             const int* __restrict__ counts, const int* __restrict__ offs,
             u16* __restrict__ H) {
    int bx = blockIdx.x;
    int job = bx >> 7;
    int mt = (bx >> 3) & 15;
    int nt = bx & 7;
    int jcnt = counts[job];
    int m0 = mt << 7;
    if (m0 >= jcnt) return;
    int joff = offs[job];
    int n0 = nt << 7;
    const u16* Bg = (job < 8) ? (wgt + (size_t)job * 1048576) : wsgt;
    const u16* Bu = (job < 8) ? (wut + (size_t)job * 1048576) : wsut;

    __shared__ __attribute__((aligned(128))) u16 As[4096];
    __shared__ __attribute__((aligned(128))) u16 Bgs[4096];
    __shared__ __attribute__((aligned(128))) u16 Bus[4096];

    int t = threadIdx.x;
    int wave = t >> 6, lane = t & 63;
    int ch = (lane & 3) * 8;                  // u16 offset of 16B chunk in row
    int r0 = (wave * 2 + 0) * 16 + (lane >> 2);
    int r1 = (wave * 2 + 1) * 16 + (lane >> 2);
    int tok0 = tlist[joff + m0 + r0];
    int tok1 = tlist[joff + m0 + r1];
    const u16* a0 = xb + (size_t)tok0 * 1024 + ch;
    const u16* a1 = xb + (size_t)tok1 * 1024 + ch;
    const u16* g0 = Bg + (size_t)(n0 + r0) * 1024 + ch;
    const u16* g1 = Bg + (size_t)(n0 + r1) * 1024 + ch;
    const u16* u0 = Bu + (size_t)(n0 + r0) * 1024 + ch;
    const u16* u1 = Bu + (size_t)(n0 + r1) * 1024 + ch;
    u16* lA0 = As  + (wave * 2 + 0) * 512;  u16* lA1 = As  + (wave * 2 + 1) * 512;
    u16* lG0 = Bgs + (wave * 2 + 0) * 512;  u16* lG1 = Bgs + (wave * 2 + 1) * 512;
    u16* lU0 = Bus + (wave * 2 + 0) * 512;  u16* lU1 = Bus + (wave * 2 + 1) * 512;

    int wm = (wave >> 1) << 6, wn = (wave & 1) << 6;
    int quad = lane >> 4, lr = lane & 15;

    f32x4 accg[4][4], accu[4][4];
    f32x4 zz = {0.f, 0.f, 0.f, 0.f};
#pragma unroll
    for (int i = 0; i < 4; i++)
#pragma unroll
        for (int j = 0; j < 4; j++) { accg[i][j] = zz; accu[i][j] = zz; }

    for (int k0 = 0; k0 < 1024; k0 += 32) {
        GLDS16(a0 + k0, lA0);  GLDS16(a1 + k0, lA1);
        GLDS16(g0 + k0, lG0);  GLDS16(g1 + k0, lG1);
        GLDS16(u0 + k0, lU0);  GLDS16(u1 + k0, lU1);
        __syncthreads();
        short8 af[4], bgf[4], buf[4];
#pragma unroll
        for (int i = 0; i < 4; i++) {
            af[i]  = *(const short8*)(As  + (wm + i * 16 + lr) * 32 + quad * 8);
            bgf[i] = *(const short8*)(Bgs + (wn + i * 16 + lr) * 32 + quad * 8);
            buf[i] = *(const short8*)(Bus + (wn + i * 16 + lr) * 32 + quad * 8);
        }
#pragma unroll
        for (int mi = 0; mi < 4; mi++)
#pragma unroll
            for (int ni = 0; ni < 4; ni++) {
                accg[mi][ni] = __builtin_amdgcn_mfma_f32_16x16x32_bf16(af[mi], bgf[ni], accg[mi][ni], 0, 0, 0);
                accu[mi][ni] = __builtin_amdgcn_mfma_f32_16x16x32_bf16(af[mi], buf[ni], accu[mi][ni], 0, 0, 0);
            }
        __syncthreads();
    }
#pragma unroll
    for (int mi = 0; mi < 4; mi++) {
        int rowb = m0 + wm + mi * 16 + quad * 4;
#pragma unroll
        for (int rr = 0; rr < 4; rr++) {
            int row = rowb + rr;
            if (row < jcnt) {
                size_t base = (size_t)(joff + row) * 1024 + n0 + wn;
#pragma unroll
                for (int ni = 0; ni < 4; ni++) {
                    float g = accg[mi][ni][rr];
                    float u = accu[mi][ni][rr];
                    float h = (g / (1.f + expf(-g))) * u;
                    H[base + ni * 16 + lr] = f2bf(h);
                }
            }
        }
    }
}

// ---------------- GEMM2: H @ Wd -> Y fp32 (unweighted, no atomics) ----------
__global__ __launch_bounds__(256, 2)
void k_gemm2(const u16* __restrict__ H, const u16* __restrict__ wdt,
             const u16* __restrict__ wsdt, const int* __restrict__ counts,
             const int* __restrict__ offs, float* __restrict__ Y) {
    int bx = blockIdx.x;
    int job = bx >> 7;
    int mt = (bx >> 3) & 15;
    int nt = bx & 7;
    int jcnt = counts[job];
    int m0 = mt << 7;
    if (m0 >= jcnt) return;
    int joff = offs[job];
    int n0 = nt << 7;
    const u16* Bt = (job < 8) ? (wdt + (size_t)job * 1048576) : wsdt;

    __shared__ __attribute__((aligned(128))) u16 As[4096];
    __shared__ __attribute__((aligned(128))) u16 Bs[4096];

    int t = threadIdx.x;
    int wave = t >> 6, lane = t & 63;
    int ch = (lane & 3) * 8;
    int r0 = (wave * 2 + 0) * 16 + (lane >> 2);
    int r1 = (wave * 2 + 1) * 16 + (lane >> 2);
    const u16* a0 = H + (size_t)(joff + m0 + r0) * 1024 + ch;
    const u16* a1 = H + (size_t)(joff + m0 + r1) * 1024 + ch;
    const u16* b0 = Bt + (size_t)(n0 + r0) * 1024 + ch;
    const u16* b1 = Bt + (size_t)(n0 + r1) * 1024 + ch;
    u16* lA0 = As + (wave * 2 + 0) * 512;  u16* lA1 = As + (wave * 2 + 1) * 512;
    u16* lB0 = Bs + (wave * 2 + 0) * 512;  u16* lB1 = Bs + (wave * 2 + 1) * 512;

    int wm = (wave >> 1) << 6, wn = (wave & 1) << 6;
    int quad = lane >> 4, lr = lane & 15;

    f32x4 acc[4][4];
    f32x4 zz = {0.f, 0.f, 0.f, 0.f};
#pragma unroll
    for (int i = 0; i < 4; i++)
#pragma unroll
        for (int j = 0; j < 4; j++) acc[i][j] = zz;

    for (int k0 = 0; k0 < 1024; k0 += 32) {
        GLDS16(a0 + k0, lA0);  GLDS16(a1 + k0, lA1);
        GLDS16(b0 + k0, lB0);  GLDS16(b1 + k0, lB1);
        __syncthreads();
        short8 af[4], bf[4];
#pragma unroll
        for (int i = 0; i < 4; i++) {
            af[i] = *(const short8*)(As + (wm + i * 16 + lr) * 32 + quad * 8);
            bf[i] = *(const short8*)(Bs + (wn + i * 16 + lr) * 32 + quad * 8);
        }
#pragma unroll
        for (int mi = 0; mi < 4; mi++)
#pragma unroll
            for (int ni = 0; ni < 4; ni++)
                acc[mi][ni] = __builtin_amdgcn_mfma_f32_16x16x32_bf16(af[mi], bf[ni], acc[mi][ni], 0, 0, 0);
        __syncthreads();
    }
#pragma unroll
    for (int mi = 0; mi < 4; mi++) {
        int rowb = m0 + wm + mi * 16 + quad * 4;
#pragma unroll
        for (int rr = 0; rr < 4; rr++) {
            int row = rowb + rr;
            if (row < jcnt) {
                float* yrow = Y + (size_t)(joff + row) * 1024 + n0 + wn;
#pragma unroll
                for (int ni = 0; ni < 4; ni++)
                    yrow[ni * 16 + lr] = acc[mi][ni][rr];
            }
        }
    }
}

// ---------------- combine: out[n] = w0*Y[s0] + w1*Y[s1] + Y[4096+n] ---------
__global__ void k_combine(const float* __restrict__ Y, const int* __restrict__ slots,
                          const float* __restrict__ tw, float* __restrict__ out) {
    int n = blockIdx.x;
    int d = threadIdx.x;
    int s0 = slots[n * 2], s1 = slots[n * 2 + 1];
    float w0 = tw[n * 2], w1 = tw[n * 2 + 1];
    f32x4 y0 = ((const f32x4*)(Y + (size_t)s0 * 1024))[d];
    f32x4 y1 = ((const f32x4*)(Y + (size_t)s1 * 1024))[d];
    f32x4 ys = ((const f32x4*)(Y + (size_t)(4096 + n) * 1024))[d];
    f32x4 r;
    r.x = w0 * y0.x + w1 * y1.x + ys.x;
    r.y = w0 * y0.y + w1 * y1.y + ys.y;
    r.z = w0 * y0.z + w1 * y1.z + ys.z;
    r.w = w0 * y0.w + w1 * y1.w + ys.w;
    ((f32x4*)(out + (size_t)n * 1024))[d] = r;
}

extern "C" void kernel_launch(void* const* d_in, const int* in_sizes, int n_in,
                              void* d_out, int out_size, void* d_ws, size_t ws_size,
                              hipStream_t stream) {
    const float* x     = (const float*)d_in[0];
    const float* wgate = (const float*)d_in[1];
    const float* wg    = (const float*)d_in[2];
    const float* wu    = (const float*)d_in[3];
    const float* wd    = (const float*)d_in[4];
    const float* wsg   = (const float*)d_in[5];
    const float* wsu   = (const float*)d_in[6];
    const float* wsd   = (const float*)d_in[7];
    float* out = (float*)d_out;

    char* ws = (char*)d_ws;
    u16*   xb    = (u16*)(ws + 0);           // 4 MB
    u16*   wgt   = (u16*)(ws + 4194304);     // 16 MB
    u16*   wut   = (u16*)(ws + 20971520);    // 16 MB
    u16*   wdt   = (u16*)(ws + 37748736);    // 16 MB
    u16*   wsgt  = (u16*)(ws + 54525952);    // 2 MB
    u16*   wsut  = (u16*)(ws + 56623104);    // 2 MB
    u16*   wsdt  = (u16*)(ws + 58720256);    // 2 MB
    u16*   H     = (u16*)(ws + 60817408);    // 12 MB
    // Y overlays wgt/wut (dead after gemm1; gemm2 runs strictly after in-stream)
    float* Y     = (float*)(ws + 4194304);   // 6144*1024*4 = 25,165,824 B
    float* Ptok  = (float*)(ws + 73400320);
    int*   tidx  = (int*)(ws + 73465856);
    float* tw    = (float*)(ws + 73482240);
    int*   tlist = (int*)(ws + 73498624);
    int*   slots = (int*)(ws + 73523200);
    int*   counts= (int*)(ws + 73539584);
    int*   offs  = (int*)(ws + 73539648);
    int*   curs  = (int*)(ws + 73539712);

    k_init<<<8, 256, 0, stream>>>(tlist, curs);
    k_cvt_x<<<2048, 256, 0, stream>>>(x, xb);
    k_cvt_w<<<27648, 256, 0, stream>>>(wg, wu, wd, wsg, wsu, wsd,
                                       wgt, wut, wdt, wsgt, wsut, wsdt);
    k_router<<<512, 256, 0, stream>>>(x, wgate, Ptok, tidx, tw);
    k_reduce<<<1, 256, 0, stream>>>(Ptok, tidx, out, counts, offs);
    k_scatter<<<8, 256, 0, stream>>>(tidx, offs, curs, tlist, slots);
    k_gemm1<<<1152, 256, 0, stream>>>(xb, wgt, wut, wsgt, wsut, tlist, counts, offs, H);
    k_gemm2<<<1152, 256, 0, stream>>>(H, wdt, wsdt, counts, offs, Y);
    k_combine<<<2048, 256, 0, stream>>>(Y, slots, tw, out);
}